// Round 12
// baseline (158.091 us; speedup 1.0000x reference)
//
#include <hip/hip_runtime.h>
#include <hip/hip_bf16.h>
#include <stdint.h>
#include <math.h>

#define KDIM 2304   // 9 * 256

typedef __attribute__((ext_vector_type(8))) short bf16x8;
typedef __attribute__((ext_vector_type(4))) float f32x4;
typedef __attribute__((ext_vector_type(2))) unsigned int u32x2;

__device__ inline unsigned short f2bf(float f) {
  union { float f; unsigned int u; } v; v.f = f;
  unsigned int u = v.u;
  unsigned int r = (u + 0x7FFFu + ((u >> 16) & 1u)) >> 16;
  return (unsigned short)r;
}
__device__ inline float bf2f(unsigned short h) {
  union { unsigned int u; float f; } v; v.u = ((unsigned int)h) << 16;
  return v.f;
}

__device__ inline void gl2lds16(const void* g, void* l) {
  __builtin_amdgcn_global_load_lds((const __attribute__((address_space(1))) void*)g,
                                   (__attribute__((address_space(3))) void*)l,
                                   16, 0, 0);
}

// volatile asm loads: compiler cannot sink them, "=v" forces the live range.
#define GLOAD16(dst, ptr) \
  asm volatile("global_load_dwordx4 %0, %1, off" : "=v"(dst) : "v"(ptr))
#define GLOAD8(dst, ptr) \
  asm volatile("global_load_dwordx2 %0, %1, off" : "=v"(dst) : "v"(ptr))

// ---------------------------------------------------------------------------
// Kernel 1: fused prep (R7 verbatim, control).
// ---------------------------------------------------------------------------
__global__ __launch_bounds__(256) void k_prep(const float* __restrict__ x,
                                              unsigned short* __restrict__ xTb,
                                              const float* __restrict__ dcn_w,
                                              const float* __restrict__ offset_w,
                                              unsigned short* __restrict__ Wpk,
                                              unsigned short* __restrict__ Wob,
                                              unsigned short* __restrict__ zp) {
  __shared__ float tile[32][65];
  int bx = (int)blockIdx.x;
  int t = threadIdx.x;
  if (bx < 2048) {
    int pt = bx & 127, ct = (bx >> 7) & 3, b = bx >> 9;
    int p0 = pt * 32, c0 = ct * 64;
    const float* xb = x + ((size_t)b << 20);
#pragma unroll
    for (int i = 0; i < 2; ++i) {
      int idx = t + i * 256;
      int c = idx >> 3, pq = idx & 7;
      float4 v = *(const float4*)(xb + ((size_t)(c0 + c) << 12) + p0 + pq * 4);
      tile[pq * 4 + 0][c] = v.x;
      tile[pq * 4 + 1][c] = v.y;
      tile[pq * 4 + 2][c] = v.z;
      tile[pq * 4 + 3][c] = v.w;
    }
    __syncthreads();
    unsigned short* ob = xTb + ((size_t)b << 20);
#pragma unroll
    for (int i = 0; i < 2; ++i) {
      int idx = t + i * 256;
      int p = idx >> 4, cg = idx & 15;
      ushort4 o;
      o.x = f2bf(tile[p][cg * 4 + 0]);
      o.y = f2bf(tile[p][cg * 4 + 1]);
      o.z = f2bf(tile[p][cg * 4 + 2]);
      o.w = f2bf(tile[p][cg * 4 + 3]);
      *(ushort4*)(ob + (((size_t)(p0 + p)) << 8) + c0 + cg * 4) = o;
    }
  } else {
    int gid = (bx - 2048) * 256 + t;
    const int N1 = 72 * 8192;
    const int N2 = 32 * KDIM;
    if (gid < N1) {
      int j = gid & 7;
      int lane = (gid >> 3) & 63;
      int mb = (gid >> 9) & 15;
      int kc = gid >> 13;
      int row = mb * 16 + (lane & 15);
      int gk = kc * 32 + ((lane >> 4) << 3) + j;
      int c = gk & 255, kidx = gk >> 8;
      Wpk[gid] = f2bf(dcn_w[((size_t)(row * 256 + c)) * 9 + kidx]);
    } else if (gid < N1 + N2) {
      int g = gid - N1;
      int ch = g / KDIM, k = g % KDIM;
      int kidx = k >> 8, c = k & 255;
      Wob[g] = (ch < 27) ? f2bf(offset_w[((size_t)(ch * 256 + c)) * 9 + kidx])
                         : (unsigned short)0;
    } else if (gid < N1 + N2 + 128) {
      zp[gid - N1 - N2] = 0;
    }
  }
}

// ---------------------------------------------------------------------------
// Kernel 2: offset conv GEMM + sampling-table epilogue (R7 verbatim, control).
// ---------------------------------------------------------------------------
__global__ __launch_bounds__(256) void k_offs(const unsigned short* __restrict__ xTb,
                                              const unsigned short* __restrict__ Wob,
                                              const unsigned short* __restrict__ zp,
                                              const float* __restrict__ offb,
                                              float* __restrict__ SW) {
  __shared__ unsigned short As[4][32 * 32];
  __shared__ unsigned short Bsf[4][32 * 32];
  __shared__ float Os[32][33];
  int t = threadIdx.x;
  int wv = t >> 6, lane = t & 63;
  int bid = (int)blockIdx.x;
  int swz = (bid & 7) * 64 + (bid >> 3);
  int n0 = swz * 32;

  int r0 = (t >> 2) & 31, coff = (t & 3) * 8;
  int rowA = n0 + r0;
  int b_ = rowA >> 12, hw = rowA & 4095, h = hw >> 6, w = hw & 63;
  int rB = ((t - 128) >> 2) & 31;

  f32x4 acc = {};

  auto stage = [&](int kt) {
    int buf = kt & 3;
    int k0 = kt * 32;
    int kidx = k0 >> 8, c0 = k0 & 255;
    if (t < 128) {
      int di = kidx / 3 - 1, dj = kidx % 3 - 1;
      int y = h + di, xx = w + dj;
      const unsigned short* g = (y >= 0 && y < 64 && xx >= 0 && xx < 64)
          ? xTb + (((((size_t)b_) << 12) + (y << 6) + xx) << 8) + c0 + coff
          : zp;
      gl2lds16(g, (char*)As[buf] + wv * 1024);
    } else {
      const unsigned short* gB = Wob + (size_t)rB * KDIM + k0 + coff;
      gl2lds16(gB, (char*)Bsf[buf] + (wv - 2) * 1024);
    }
  };

  stage(0); stage(1); stage(2);

  int mf = wv & 1, nf = wv >> 1;
  for (int kt = 0; kt < 72; ++kt) {
    if (kt <= 69)      asm volatile("s_waitcnt vmcnt(2)" ::: "memory");
    else if (kt == 70) asm volatile("s_waitcnt vmcnt(1)" ::: "memory");
    else               asm volatile("s_waitcnt vmcnt(0)" ::: "memory");
    asm volatile("s_barrier" ::: "memory");
    if (kt + 3 < 72) stage(kt + 3);
    int buf = kt & 3;
    bf16x8 aF = *(const bf16x8*)(As[buf] + (mf * 16 + (lane & 15)) * 32 + (lane >> 4) * 8);
    bf16x8 bF = *(const bf16x8*)(Bsf[buf] + (nf * 16 + (lane & 15)) * 32 + (lane >> 4) * 8);
    acc = __builtin_amdgcn_mfma_f32_16x16x32_bf16(aF, bF, acc, 0, 0, 0);

    asm volatile("s_barrier" ::: "memory");
  }

  int quad = lane >> 4, cl = lane & 15;
#pragma unroll
  for (int rr = 0; rr < 4; ++rr)
    Os[mf * 16 + quad * 4 + rr][nf * 16 + cl] = acc[rr];
  __syncthreads();

  for (int item = t; item < 288; item += 256) {
    int bl = item & 31, k = item >> 5;
    int bhw = n0 + bl;
    int h_ = (bhw >> 6) & 63, w_ = bhw & 63;
    float dy = Os[bl][2 * k]     + offb[2 * k];
    float dx = Os[bl][2 * k + 1] + offb[2 * k + 1];
    float mv = Os[bl][18 + k]    + offb[18 + k];
    float mask = 1.0f / (1.0f + expf(-mv));

    float py = (float)(h_ - 1 + k / 3) + dy;
    float px = (float)(w_ - 1 + k % 3) + dx;
    float y0f = floorf(py), x0f = floorf(px);
    float wy = py - y0f, wx = px - x0f;
    int y0 = (int)y0f, x0 = (int)x0f;
    int y1 = y0 + 1, x1 = x0 + 1;

    float vy0 = (y0 >= 0 && y0 < 64) ? 1.f : 0.f;
    float vy1 = (y1 >= 0 && y1 < 64) ? 1.f : 0.f;
    float vx0 = (x0 >= 0 && x0 < 64) ? 1.f : 0.f;
    float vx1 = (x1 >= 0 && x1 < 64) ? 1.f : 0.f;
    int y0c = min(max(y0, 0), 63), y1c = min(max(y1, 0), 63);
    int x0c = min(max(x0, 0), 63), x1c = min(max(x1, 0), 63);

    float4 wv4;
    wv4.x = (1.f - wy) * (1.f - wx) * vy0 * vx0 * mask;
    wv4.y = (1.f - wy) * wx * vy0 * vx1 * mask;
    wv4.z = wy * (1.f - wx) * vy1 * vx0 * mask;
    wv4.w = wy * wx * vy1 * vx1 * mask;
    uint4 ov;
    ov.x = (unsigned)(((y0c << 6) + x0c) << 8);
    ov.y = (unsigned)(((y0c << 6) + x1c) << 8);
    ov.z = (unsigned)(((y1c << 6) + x0c) << 8);
    ov.w = (unsigned)(((y1c << 6) + x1c) << 8);

    float* p = SW + (size_t)(k * 16384 + bhw) * 8;
    *(float4*)p = wv4;
    *(uint4*)(p + 4) = ov;
  }
}

// ---------------------------------------------------------------------------
// Kernel 3: fused sample + main GEMM -- R7 structure at 1024 THREADS
//  (16 waves, 4/SIMD: doubles in-flight loads per CU for L2 queue depth).
//  Same BM=256 x BN=64 tile, grid 256, same phase count (36) and the SAME
//  vmcnt ledger as R7 (per-thread load counts unchanged: 4 q + 8 aF /phase).
//  Waves: wm = wv&3 (4 m-blocks each), wn = wv>>2 (one 16-col frag).
//  Sampling: 16 thr/row -> 4-channel blends, 8B gathers (same line count).
// ---------------------------------------------------------------------------
#define PHASE(PH, Q, AF, BUF, WB, WM)                                          \
  do {                                                                         \
    if (((PH) & 3) == 0) {                                                     \
      int g_ = (PH) >> 2;                                                      \
      wv4 = *(const float4*)(SWL + (size_t)(g_ * 128 + r * 2) * 4);            \
      ov  = *(const uint4*)(SWL + (size_t)(g_ * 128 + r * 2 + 1) * 4);         \
    } else if (((PH) & 3) == 2 && (PH) < 32) {                                 \
      ov  = *(const uint4*)(SWL + (size_t)((((PH) >> 2) + 1) * 128 + r * 2 + 1) * 4); \
    }                                                                          \
    asm volatile("s_waitcnt vmcnt(" #WB ")" ::: "memory");                     \
    __builtin_amdgcn_sched_barrier(0);                                         \
    {                                                                          \
      union U_ { u32x2 d; unsigned short u[4]; };                              \
      U_ q0_, q1_, q2_, q3_;                                                   \
      q0_.d = Q[0]; q1_.d = Q[1]; q2_.d = Q[2]; q3_.d = Q[3];                  \
      float s_[4];                                                             \
      _Pragma("unroll")                                                        \
      for (int j_ = 0; j_ < 4; ++j_)                                           \
        s_[j_] = wv4.x * bf2f(q0_.u[j_]) + wv4.y * bf2f(q1_.u[j_]) +           \
                 wv4.z * bf2f(q2_.u[j_]) + wv4.w * bf2f(q3_.u[j_]);            \
      union { __hip_bfloat162 h2[2]; ushort4 v; } pk_;                         \
      pk_.h2[0] = __float22bfloat162_rn(make_float2(s_[0], s_[1]));            \
      pk_.h2[1] = __float22bfloat162_rn(make_float2(s_[2], s_[3]));            \
      *(ushort4*)(&Bs[BUF][s_th][bsw]) = pk_.v;                                \
    }                                                                          \
    if ((PH) < 34) {                                                           \
      int kn0_ = 2 * (PH) + 4;                                                 \
      unsigned c_ = (unsigned)((((kn0_ & 7) + s_th) << 5) + gg * 4);           \
      GLOAD8(Q[0], xb + ov.x + c_);                                            \
      GLOAD8(Q[1], xb + ov.y + c_);                                            \
      GLOAD8(Q[2], xb + ov.z + c_);                                            \
      GLOAD8(Q[3], xb + ov.w + c_);                                            \
    }                                                                          \
    asm volatile("s_waitcnt vmcnt(" #WM ") lgkmcnt(0)\n\ts_barrier" ::: "memory"); \
    __builtin_amdgcn_sched_barrier(0);                                         \
    _Pragma("unroll")                                                          \
    for (int s2_ = 0; s2_ < 2; ++s2_) {                                        \
      bf16x8 bF_ = *(const bf16x8*)(                                           \
          &Bs[BUF][s2_][(wn * 16 + (lane & 15)) * 56 + (lane >> 4) * 8]);      \
      _Pragma("unroll")                                                        \
      for (int i_ = 0; i_ < 4; ++i_)                                           \
        acc[i_] = __builtin_amdgcn_mfma_f32_16x16x32_bf16(                     \
            AF[s2_ * 4 + i_], bF_, acc[i_], 0, 0, 0);                          \
    }                                                                          \
    if ((PH) < 34) {                                                           \
      _Pragma("unroll")                                                        \
      for (int i_ = 0; i_ < 8; ++i_) {                                         \
        const unsigned short* ap_ =                                            \
            wpBase + ((size_t)((2 * (PH) + 4 + (i_ >> 2)) * 16 + (i_ & 3))) * 512; \
        GLOAD16(AF[i_], ap_);                                                  \
      }                                                                        \
    }                                                                          \
  } while (0)

__global__ __launch_bounds__(1024, 2) void k_fused(const unsigned short* __restrict__ Wpk,
                                                   const unsigned short* __restrict__ xTb,
                                                   const float* __restrict__ SW,
                                                   float* __restrict__ out) {
  __shared__ __align__(16) unsigned short Bs[2][2][64 * 56];  // 28 KB
  __shared__ __align__(16) float SWL[1152 * 4];               // 18 KB
  int t = threadIdx.x;
  int wv = t >> 6, lane = t & 63;
  int wm = wv & 3, wn = wv >> 2;   // wn 0..3
  int bid = (int)blockIdx.x;
  int swz = (bid & 7) * 32 + (bid >> 3);   // XCD-contiguous chunks (256 = 8*32)
  int n0 = swz * 64;
  int b  = n0 >> 12;
  const unsigned short* xb = xTb + ((size_t)b << 20);

  // sampling role: row r (0..63); u = t&15 -> substep s_th, ch-quad gg (4 ch)
  int r = t >> 4;
  int u = t & 15;
  int s_th = u & 1, gg = u >> 1;   // gg 0..7
  int bsw = r * 56 + gg * 4;

  const unsigned short* wpBase = Wpk + ((size_t)(wm * 4 * 64 + lane)) * 8;

  f32x4 acc[4] = {};

  // --- stage SW table (64 rows x 9 groups x 32B = 18KB) into LDS ---
  {
#pragma unroll
    for (int i = 0; i < 2; ++i) {
      int hs = t + i * 1024;
      if (hs < 1152) {                     // i=1: t<128 -> waves 0,1 (uniform)
        int grp = hs >> 7, row = (hs >> 1) & 63, hh = hs & 1;
        const float* src = SW + ((size_t)(grp * 16384 + n0 + row)) * 8 + hh * 4;
        char* dstbase = (char*)SWL + ((size_t)((t & ~63) + i * 1024)) * 16;
        gl2lds16(src, dstbase);
      }
    }
  }
  asm volatile("s_waitcnt vmcnt(0)" ::: "memory");
  __builtin_amdgcn_s_barrier();

  float4 wv4; uint4 ov;
  wv4 = *(const float4*)(SWL + (size_t)(r * 2) * 4);
  ov  = *(const uint4*)(SWL + (size_t)(r * 2 + 1) * 4);

  u32x2 qA[4], qB[4];
  bf16x8 aFA[8], aFB[8];

  // prologue loads in canonical order: q(0), aF(0), q(1), aF(1)
  {
    unsigned cA = (unsigned)((s_th << 5) + gg * 4);
    GLOAD8(qA[0], xb + ov.x + cA);
    GLOAD8(qA[1], xb + ov.y + cA);
    GLOAD8(qA[2], xb + ov.z + cA);
    GLOAD8(qA[3], xb + ov.w + cA);
#pragma unroll
    for (int i = 0; i < 8; ++i) {
      const unsigned short* ap = wpBase + ((size_t)(((i >> 2)) * 16 + (i & 3))) * 512;
      GLOAD16(aFA[i], ap);
    }
    unsigned cB = (unsigned)(((2 + s_th) << 5) + gg * 4);
    GLOAD8(qB[0], xb + ov.x + cB);
    GLOAD8(qB[1], xb + ov.y + cB);
    GLOAD8(qB[2], xb + ov.z + cB);
    GLOAD8(qB[3], xb + ov.w + cB);
#pragma unroll
    for (int i = 0; i < 8; ++i) {
      const unsigned short* ap = wpBase + ((size_t)((2 + (i >> 2)) * 16 + (i & 3))) * 512;
      GLOAD16(aFB[i], ap);
    }
  }

  for (int ph = 0; ph < 34; ph += 2) {       // phases 0..33
    PHASE(ph,     qA, aFA, 0, 20, 16);
    PHASE(ph + 1, qB, aFB, 1, 20, 16);
  }
  PHASE(34, qA, aFA, 0, 20, 12);
  PHASE(35, qB, aFB, 1, 8, 0);

  // epilogue
  int quad = lane >> 4, cl = lane & 15;
  float* ob = out + (((size_t)b) << 20);
#pragma unroll
  for (int i = 0; i < 4; ++i) {
    int mbase = wm * 64 + i * 16 + quad * 4;
    int hw = (n0 & 4095) + wn * 16 + cl;
    float* op = ob + hw;
#pragma unroll
    for (int rr = 0; rr < 4; ++rr)
      op[((size_t)(mbase + rr)) << 12] = acc[i][rr];
  }
}

// ---------------------------------------------------------------------------
extern "C" void kernel_launch(void* const* d_in, const int* in_sizes, int n_in,
                              void* d_out, int out_size, void* d_ws, size_t ws_size,
                              hipStream_t stream) {
  const float* x        = (const float*)d_in[0];
  const float* offset_w = (const float*)d_in[1];
  const float* offset_b = (const float*)d_in[2];
  const float* dcn_w    = (const float*)d_in[3];
  float* out = (float*)d_out;

  char* ws = (char*)d_ws;
  size_t off = 0;
  auto carve = [&](size_t bytes) -> void* {
    void* p = ws + off;
    off += (bytes + 255) & ~(size_t)255;
    return p;
  };
  unsigned short* xTb = (unsigned short*)carve(4ull * 64 * 64 * 256 * 2);   // 8 MB
  unsigned short* Wpk = (unsigned short*)carve(72ull * 8192 * 2);           // 1.125 MB
  unsigned short* Wob = (unsigned short*)carve(32ull * KDIM * 2);           // 144 KB
  unsigned short* zp  = (unsigned short*)carve(256);                        // zero page
  float*          SW  = (float*)carve(9ull * 16384 * 8 * 4);                // 4.5 MB
  (void)ws_size; (void)in_sizes; (void)n_in; (void)out_size;

  const int WPREP_BLOCKS = (72 * 8192 + 32 * KDIM + 128 + 255) / 256;
  k_prep<<<dim3(2048 + WPREP_BLOCKS), 256, 0, stream>>>(
      x, xTb, dcn_w, offset_w, Wpk, Wob, zp);
  k_offs<<<dim3(512), 256, 0, stream>>>(xTb, Wob, zp, offset_b, SW);
  k_fused<<<dim3(256), 1024, 0, stream>>>(Wpk, xTb, SW, out);
}

// Round 13
// 132.497 us; speedup vs baseline: 1.1932x; 1.1932x over previous
//
#include <hip/hip_runtime.h>
#include <hip/hip_bf16.h>
#include <stdint.h>
#include <math.h>

#define KDIM 2304   // 9 * 256

typedef __attribute__((ext_vector_type(8))) short bf16x8;
typedef __attribute__((ext_vector_type(4))) float f32x4;

__device__ inline unsigned short f2bf(float f) {
  union { float f; unsigned int u; } v; v.f = f;
  unsigned int u = v.u;
  unsigned int r = (u + 0x7FFFu + ((u >> 16) & 1u)) >> 16;
  return (unsigned short)r;
}
__device__ inline float bf2f(unsigned short h) {
  union { unsigned int u; float f; } v; v.u = ((unsigned int)h) << 16;
  return v.f;
}

__device__ inline void gl2lds16(const void* g, void* l) {
  __builtin_amdgcn_global_load_lds((const __attribute__((address_space(1))) void*)g,
                                   (__attribute__((address_space(3))) void*)l,
                                   16, 0, 0);
}

// volatile asm load: compiler cannot sink it, "=v" forces the live range.
#define GLOAD16(dst, ptr) \
  asm volatile("global_load_dwordx4 %0, %1, off" : "=v"(dst) : "v"(ptr))

// ---------------------------------------------------------------------------
// Kernel 1: fused prep (R7 verbatim).
// ---------------------------------------------------------------------------
__global__ __launch_bounds__(256) void k_prep(const float* __restrict__ x,
                                              unsigned short* __restrict__ xTb,
                                              const float* __restrict__ dcn_w,
                                              const float* __restrict__ offset_w,
                                              unsigned short* __restrict__ Wpk,
                                              unsigned short* __restrict__ Wob,
                                              unsigned short* __restrict__ zp) {
  __shared__ float tile[32][65];
  int bx = (int)blockIdx.x;
  int t = threadIdx.x;
  if (bx < 2048) {
    int pt = bx & 127, ct = (bx >> 7) & 3, b = bx >> 9;
    int p0 = pt * 32, c0 = ct * 64;
    const float* xb = x + ((size_t)b << 20);
#pragma unroll
    for (int i = 0; i < 2; ++i) {
      int idx = t + i * 256;
      int c = idx >> 3, pq = idx & 7;
      float4 v = *(const float4*)(xb + ((size_t)(c0 + c) << 12) + p0 + pq * 4);
      tile[pq * 4 + 0][c] = v.x;
      tile[pq * 4 + 1][c] = v.y;
      tile[pq * 4 + 2][c] = v.z;
      tile[pq * 4 + 3][c] = v.w;
    }
    __syncthreads();
    unsigned short* ob = xTb + ((size_t)b << 20);
#pragma unroll
    for (int i = 0; i < 2; ++i) {
      int idx = t + i * 256;
      int p = idx >> 4, cg = idx & 15;
      ushort4 o;
      o.x = f2bf(tile[p][cg * 4 + 0]);
      o.y = f2bf(tile[p][cg * 4 + 1]);
      o.z = f2bf(tile[p][cg * 4 + 2]);
      o.w = f2bf(tile[p][cg * 4 + 3]);
      *(ushort4*)(ob + (((size_t)(p0 + p)) << 8) + c0 + cg * 4) = o;
    }
  } else {
    int gid = (bx - 2048) * 256 + t;
    const int N1 = 72 * 8192;
    const int N2 = 32 * KDIM;
    if (gid < N1) {
      int j = gid & 7;
      int lane = (gid >> 3) & 63;
      int mb = (gid >> 9) & 15;
      int kc = gid >> 13;
      int row = mb * 16 + (lane & 15);
      int gk = kc * 32 + ((lane >> 4) << 3) + j;
      int c = gk & 255, kidx = gk >> 8;
      Wpk[gid] = f2bf(dcn_w[((size_t)(row * 256 + c)) * 9 + kidx]);
    } else if (gid < N1 + N2) {
      int g = gid - N1;
      int ch = g / KDIM, k = g % KDIM;
      int kidx = k >> 8, c = k & 255;
      Wob[g] = (ch < 27) ? f2bf(offset_w[((size_t)(ch * 256 + c)) * 9 + kidx])
                         : (unsigned short)0;
    } else if (gid < N1 + N2 + 128) {
      zp[gid - N1 - N2] = 0;
    }
  }
}

// ---------------------------------------------------------------------------
// Kernel 2: offset conv GEMM + sampling-table epilogue (R7 verbatim:
//  grid 512, 256 thr / 4 waves, BK=32, 4-buffer depth-3, ONE barrier/iter).
// ---------------------------------------------------------------------------
__global__ __launch_bounds__(256) void k_offs(const unsigned short* __restrict__ xTb,
                                              const unsigned short* __restrict__ Wob,
                                              const unsigned short* __restrict__ zp,
                                              const float* __restrict__ offb,
                                              float* __restrict__ SW) {
  __shared__ unsigned short As[4][32 * 32];
  __shared__ unsigned short Bsf[4][32 * 32];
  __shared__ float Os[32][33];
  int t = threadIdx.x;
  int wv = t >> 6, lane = t & 63;
  int bid = (int)blockIdx.x;
  int swz = (bid & 7) * 64 + (bid >> 3);
  int n0 = swz * 32;

  int r0 = (t >> 2) & 31, coff = (t & 3) * 8;
  int rowA = n0 + r0;
  int b_ = rowA >> 12, hw = rowA & 4095, h = hw >> 6, w = hw & 63;
  int rB = ((t - 128) >> 2) & 31;

  f32x4 acc = {};

  auto stage = [&](int kt) {
    int buf = kt & 3;
    int k0 = kt * 32;
    int kidx = k0 >> 8, c0 = k0 & 255;
    if (t < 128) {
      int di = kidx / 3 - 1, dj = kidx % 3 - 1;
      int y = h + di, xx = w + dj;
      const unsigned short* g = (y >= 0 && y < 64 && xx >= 0 && xx < 64)
          ? xTb + (((((size_t)b_) << 12) + (y << 6) + xx) << 8) + c0 + coff
          : zp;
      gl2lds16(g, (char*)As[buf] + wv * 1024);
    } else {
      const unsigned short* gB = Wob + (size_t)rB * KDIM + k0 + coff;
      gl2lds16(gB, (char*)Bsf[buf] + (wv - 2) * 1024);
    }
  };

  stage(0); stage(1); stage(2);

  int mf = wv & 1, nf = wv >> 1;
  for (int kt = 0; kt < 72; ++kt) {
    if (kt <= 69)      asm volatile("s_waitcnt vmcnt(2)" ::: "memory");
    else if (kt == 70) asm volatile("s_waitcnt vmcnt(1)" ::: "memory");
    else               asm volatile("s_waitcnt vmcnt(0)" ::: "memory");
    asm volatile("s_barrier" ::: "memory");
    if (kt + 3 < 72) stage(kt + 3);
    int buf = kt & 3;
    bf16x8 aF = *(const bf16x8*)(As[buf] + (mf * 16 + (lane & 15)) * 32 + (lane >> 4) * 8);
    bf16x8 bF = *(const bf16x8*)(Bsf[buf] + (nf * 16 + (lane & 15)) * 32 + (lane >> 4) * 8);
    acc = __builtin_amdgcn_mfma_f32_16x16x32_bf16(aF, bF, acc, 0, 0, 0);
  }

  int quad = lane >> 4, cl = lane & 15;
#pragma unroll
  for (int rr = 0; rr < 4; ++rr)
    Os[mf * 16 + quad * 4 + rr][nf * 16 + cl] = acc[rr];
  __syncthreads();

  for (int item = t; item < 288; item += 256) {
    int bl = item & 31, k = item >> 5;
    int bhw = n0 + bl;
    int h_ = (bhw >> 6) & 63, w_ = bhw & 63;
    float dy = Os[bl][2 * k]     + offb[2 * k];
    float dx = Os[bl][2 * k + 1] + offb[2 * k + 1];
    float mv = Os[bl][18 + k]    + offb[18 + k];
    float mask = 1.0f / (1.0f + expf(-mv));

    float py = (float)(h_ - 1 + k / 3) + dy;
    float px = (float)(w_ - 1 + k % 3) + dx;
    float y0f = floorf(py), x0f = floorf(px);
    float wy = py - y0f, wx = px - x0f;
    int y0 = (int)y0f, x0 = (int)x0f;
    int y1 = y0 + 1, x1 = x0 + 1;

    float vy0 = (y0 >= 0 && y0 < 64) ? 1.f : 0.f;
    float vy1 = (y1 >= 0 && y1 < 64) ? 1.f : 0.f;
    float vx0 = (x0 >= 0 && x0 < 64) ? 1.f : 0.f;
    float vx1 = (x1 >= 0 && x1 < 64) ? 1.f : 0.f;
    int y0c = min(max(y0, 0), 63), y1c = min(max(y1, 0), 63);
    int x0c = min(max(x0, 0), 63), x1c = min(max(x1, 0), 63);

    float4 wv4;
    wv4.x = (1.f - wy) * (1.f - wx) * vy0 * vx0 * mask;
    wv4.y = (1.f - wy) * wx * vy0 * vx1 * mask;
    wv4.z = wy * (1.f - wx) * vy1 * vx0 * mask;
    wv4.w = wy * wx * vy1 * vx1 * mask;
    uint4 ov;
    ov.x = (unsigned)(((y0c << 6) + x0c) << 8);
    ov.y = (unsigned)(((y0c << 6) + x1c) << 8);
    ov.z = (unsigned)(((y1c << 6) + x0c) << 8);
    ov.w = (unsigned)(((y1c << 6) + x1c) << 8);

    float* p = SW + (size_t)(k * 16384 + bhw) * 8;
    *(float4*)p = wv4;
    *(uint4*)(p + 4) = ov;
  }
}

// ---------------------------------------------------------------------------
// Kernel 3: fused sample + main GEMM -- R7 + T5 s_setprio around MFMA cluster
//  (single-variable change; T5 prerequisite = counted-vmcnt phase-split
//   schedule with wave role diversity, which this structure has).
// ---------------------------------------------------------------------------
#define PHASE(PH, Q, AF, BUF, WB, WM)                                          \
  do {                                                                         \
    if (((PH) & 3) == 0) {                                                     \
      int g_ = (PH) >> 2;                                                      \
      wv4 = *(const float4*)(SWL + (size_t)(g_ * 128 + r * 2) * 4);            \
      ov  = *(const uint4*)(SWL + (size_t)(g_ * 128 + r * 2 + 1) * 4);         \
    } else if (((PH) & 3) == 2 && (PH) < 32) {                                 \
      ov  = *(const uint4*)(SWL + (size_t)((((PH) >> 2) + 1) * 128 + r * 2 + 1) * 4); \
    }                                                                          \
    asm volatile("s_waitcnt vmcnt(" #WB ")" ::: "memory");                     \
    __builtin_amdgcn_sched_barrier(0);                                         \
    float s_[8];                                                               \
    _Pragma("unroll")                                                          \
    for (int j_ = 0; j_ < 8; ++j_)                                             \
      s_[j_] = wv4.x * bf2f((unsigned short)Q[0][j_]) +                        \
               wv4.y * bf2f((unsigned short)Q[1][j_]) +                        \
               wv4.z * bf2f((unsigned short)Q[2][j_]) +                        \
               wv4.w * bf2f((unsigned short)Q[3][j_]);                         \
    union { __hip_bfloat162 h2[4]; bf16x8 v; } pk_;                            \
    pk_.h2[0] = __float22bfloat162_rn(make_float2(s_[0], s_[1]));              \
    pk_.h2[1] = __float22bfloat162_rn(make_float2(s_[2], s_[3]));              \
    pk_.h2[2] = __float22bfloat162_rn(make_float2(s_[4], s_[5]));              \
    pk_.h2[3] = __float22bfloat162_rn(make_float2(s_[6], s_[7]));              \
    *(bf16x8*)(&Bs[BUF][s_th][bsw]) = pk_.v;                                   \
    if ((PH) < 34) {                                                           \
      int kn0_ = 2 * (PH) + 4;                                                 \
      unsigned c_ = (unsigned)((((kn0_ & 7) + s_th) << 5) + gg * 8);           \
      GLOAD16(Q[0], xb + ov.x + c_);                                           \
      GLOAD16(Q[1], xb + ov.y + c_);                                           \
      GLOAD16(Q[2], xb + ov.z + c_);                                           \
      GLOAD16(Q[3], xb + ov.w + c_);                                           \
    }                                                                          \
    asm volatile("s_waitcnt vmcnt(" #WM ") lgkmcnt(0)\n\ts_barrier" ::: "memory"); \
    __builtin_amdgcn_sched_barrier(0);                                         \
    __builtin_amdgcn_s_setprio(1);                                             \
    _Pragma("unroll")                                                          \
    for (int s2_ = 0; s2_ < 2; ++s2_) {                                        \
      bf16x8 bF0_ = *(const bf16x8*)(                                          \
          &Bs[BUF][s2_][(wn * 32 + (lane & 15)) * 56 + (lane >> 4) * 8]);      \
      bf16x8 bF1_ = *(const bf16x8*)(                                          \
          &Bs[BUF][s2_][(wn * 32 + 16 + (lane & 15)) * 56 + (lane >> 4) * 8]); \
      _Pragma("unroll")                                                        \
      for (int i_ = 0; i_ < 4; ++i_) {                                         \
        acc[i_][0] = __builtin_amdgcn_mfma_f32_16x16x32_bf16(                  \
            AF[s2_ * 4 + i_], bF0_, acc[i_][0], 0, 0, 0);                      \
        acc[i_][1] = __builtin_amdgcn_mfma_f32_16x16x32_bf16(                  \
            AF[s2_ * 4 + i_], bF1_, acc[i_][1], 0, 0, 0);                      \
      }                                                                        \
    }                                                                          \
    __builtin_amdgcn_s_setprio(0);                                             \
    if ((PH) < 34) {                                                           \
      _Pragma("unroll")                                                        \
      for (int i_ = 0; i_ < 8; ++i_) {                                         \
        const unsigned short* ap_ =                                            \
            wpBase + ((size_t)((2 * (PH) + 4 + (i_ >> 2)) * 16 + (i_ & 3))) * 512; \
        GLOAD16(AF[i_], ap_);                                                  \
      }                                                                        \
    }                                                                          \
  } while (0)

__global__ __launch_bounds__(512, 2) void k_fused(const unsigned short* __restrict__ Wpk,
                                                  const unsigned short* __restrict__ xTb,
                                                  const float* __restrict__ SW,
                                                  float* __restrict__ out) {
  __shared__ __align__(16) unsigned short Bs[2][2][64 * 56];  // 28 KB
  __shared__ __align__(16) float SWL[1152 * 4];               // 18 KB
  int t = threadIdx.x;
  int wv = t >> 6, lane = t & 63;
  int wm = wv & 3, wn = wv >> 2;
  int bid = (int)blockIdx.x;
  int swz = (bid & 7) * 32 + (bid >> 3);   // XCD-contiguous chunks (256 = 8*32)
  int n0 = swz * 64;
  int b  = n0 >> 12;
  const unsigned short* xb = xTb + ((size_t)b << 20);

  // sampling role: row r (0..63); u = t&7 -> substep s_th, ch-group gg (8 ch)
  int r = t >> 3;
  int u = t & 7;
  int s_th = u & 1, gg = u >> 1;
  int bsw = r * 56 + gg * 8;

  const unsigned short* wpBase = Wpk + ((size_t)(wm * 4 * 64 + lane)) * 8;

  f32x4 acc[4][2] = {};

  // --- stage SW table (64 rows x 9 groups x 32B = 18KB) into LDS ---
  {
#pragma unroll
    for (int i = 0; i < 3; ++i) {
      int hs = t + i * 512;
      if (hs < 1152) {
        int grp = hs >> 7, row = (hs >> 1) & 63, hh = hs & 1;
        const float* src = SW + ((size_t)(grp * 16384 + n0 + row)) * 8 + hh * 4;
        char* dstbase = (char*)SWL + ((size_t)((t & ~63) + i * 512)) * 16;
        gl2lds16(src, dstbase);
      }
    }
  }
  asm volatile("s_waitcnt vmcnt(0)" ::: "memory");
  __builtin_amdgcn_s_barrier();

  float4 wv4; uint4 ov;
  wv4 = *(const float4*)(SWL + (size_t)(r * 2) * 4);
  ov  = *(const uint4*)(SWL + (size_t)(r * 2 + 1) * 4);

  bf16x8 qA[4], qB[4];
  bf16x8 aFA[8], aFB[8];

  // prologue loads in canonical order: q(0), aF(0), q(1), aF(1)
  {
    unsigned cA = (unsigned)((s_th << 5) + gg * 8);
    GLOAD16(qA[0], xb + ov.x + cA);
    GLOAD16(qA[1], xb + ov.y + cA);
    GLOAD16(qA[2], xb + ov.z + cA);
    GLOAD16(qA[3], xb + ov.w + cA);
#pragma unroll
    for (int i = 0; i < 8; ++i) {
      const unsigned short* ap = wpBase + ((size_t)(((i >> 2)) * 16 + (i & 3))) * 512;
      GLOAD16(aFA[i], ap);
    }
    unsigned cB = (unsigned)(((2 + s_th) << 5) + gg * 8);
    GLOAD16(qB[0], xb + ov.x + cB);
    GLOAD16(qB[1], xb + ov.y + cB);
    GLOAD16(qB[2], xb + ov.z + cB);
    GLOAD16(qB[3], xb + ov.w + cB);
#pragma unroll
    for (int i = 0; i < 8; ++i) {
      const unsigned short* ap = wpBase + ((size_t)((2 + (i >> 2)) * 16 + (i & 3))) * 512;
      GLOAD16(aFB[i], ap);
    }
  }

  for (int ph = 0; ph < 34; ph += 2) {       // phases 0..33
    PHASE(ph,     qA, aFA, 0, 20, 16);
    PHASE(ph + 1, qB, aFB, 1, 20, 16);
  }
  PHASE(34, qA, aFA, 0, 20, 12);
  PHASE(35, qB, aFB, 1, 8, 0);

  // epilogue
  int quad = lane >> 4, cl = lane & 15;
  float* ob = out + (((size_t)b) << 20);
#pragma unroll
  for (int i = 0; i < 4; ++i) {
    int mbase = wm * 64 + i * 16 + quad * 4;
#pragma unroll
    for (int j = 0; j < 2; ++j) {
      int hw = (n0 & 4095) + wn * 32 + j * 16 + cl;
      float* op = ob + hw;
#pragma unroll
      for (int rr = 0; rr < 4; ++rr)
        op[((size_t)(mbase + rr)) << 12] = acc[i][j][rr];
    }
  }
}

// ---------------------------------------------------------------------------
extern "C" void kernel_launch(void* const* d_in, const int* in_sizes, int n_in,
                              void* d_out, int out_size, void* d_ws, size_t ws_size,
                              hipStream_t stream) {
  const float* x        = (const float*)d_in[0];
  const float* offset_w = (const float*)d_in[1];
  const float* offset_b = (const float*)d_in[2];
  const float* dcn_w    = (const float*)d_in[3];
  float* out = (float*)d_out;

  char* ws = (char*)d_ws;
  size_t off = 0;
  auto carve = [&](size_t bytes) -> void* {
    void* p = ws + off;
    off += (bytes + 255) & ~(size_t)255;
    return p;
  };
  unsigned short* xTb = (unsigned short*)carve(4ull * 64 * 64 * 256 * 2);   // 8 MB
  unsigned short* Wpk = (unsigned short*)carve(72ull * 8192 * 2);           // 1.125 MB
  unsigned short* Wob = (unsigned short*)carve(32ull * KDIM * 2);           // 144 KB
  unsigned short* zp  = (unsigned short*)carve(256);                        // zero page
  float*          SW  = (float*)carve(9ull * 16384 * 8 * 4);                // 4.5 MB
  (void)ws_size; (void)in_sizes; (void)n_in; (void)out_size;

  const int WPREP_BLOCKS = (72 * 8192 + 32 * KDIM + 128 + 255) / 256;
  k_prep<<<dim3(2048 + WPREP_BLOCKS), 256, 0, stream>>>(
      x, xTb, dcn_w, offset_w, Wpk, Wob, zp);
  k_offs<<<dim3(512), 256, 0, stream>>>(xTb, Wob, zp, offset_b, SW);
  k_fused<<<dim3(256), 512, 0, stream>>>(Wpk, xTb, SW, out);
}

// Round 14
// 132.065 us; speedup vs baseline: 1.1971x; 1.0033x over previous
//
#include <hip/hip_runtime.h>
#include <hip/hip_bf16.h>
#include <stdint.h>
#include <math.h>

#define KDIM 2304   // 9 * 256

typedef __attribute__((ext_vector_type(8))) short bf16x8;
typedef __attribute__((ext_vector_type(4))) float f32x4;

__device__ inline unsigned short f2bf(float f) {
  union { float f; unsigned int u; } v; v.f = f;
  unsigned int u = v.u;
  unsigned int r = (u + 0x7FFFu + ((u >> 16) & 1u)) >> 16;
  return (unsigned short)r;
}
__device__ inline float bf2f(unsigned short h) {
  union { unsigned int u; float f; } v; v.u = ((unsigned int)h) << 16;
  return v.f;
}

__device__ inline void gl2lds16(const void* g, void* l) {
  __builtin_amdgcn_global_load_lds((const __attribute__((address_space(1))) void*)g,
                                   (__attribute__((address_space(3))) void*)l,
                                   16, 0, 0);
}

// volatile asm load: compiler cannot sink it, "=v" forces the live range.
#define GLOAD16(dst, ptr) \
  asm volatile("global_load_dwordx4 %0, %1, off" : "=v"(dst) : "v"(ptr))

// ---------------------------------------------------------------------------
// Kernel 1: fused prep (R7 verbatim).
// ---------------------------------------------------------------------------
__global__ __launch_bounds__(256) void k_prep(const float* __restrict__ x,
                                              unsigned short* __restrict__ xTb,
                                              const float* __restrict__ dcn_w,
                                              const float* __restrict__ offset_w,
                                              unsigned short* __restrict__ Wpk,
                                              unsigned short* __restrict__ Wob,
                                              unsigned short* __restrict__ zp) {
  __shared__ float tile[32][65];
  int bx = (int)blockIdx.x;
  int t = threadIdx.x;
  if (bx < 2048) {
    int pt = bx & 127, ct = (bx >> 7) & 3, b = bx >> 9;
    int p0 = pt * 32, c0 = ct * 64;
    const float* xb = x + ((size_t)b << 20);
#pragma unroll
    for (int i = 0; i < 2; ++i) {
      int idx = t + i * 256;
      int c = idx >> 3, pq = idx & 7;
      float4 v = *(const float4*)(xb + ((size_t)(c0 + c) << 12) + p0 + pq * 4);
      tile[pq * 4 + 0][c] = v.x;
      tile[pq * 4 + 1][c] = v.y;
      tile[pq * 4 + 2][c] = v.z;
      tile[pq * 4 + 3][c] = v.w;
    }
    __syncthreads();
    unsigned short* ob = xTb + ((size_t)b << 20);
#pragma unroll
    for (int i = 0; i < 2; ++i) {
      int idx = t + i * 256;
      int p = idx >> 4, cg = idx & 15;
      ushort4 o;
      o.x = f2bf(tile[p][cg * 4 + 0]);
      o.y = f2bf(tile[p][cg * 4 + 1]);
      o.z = f2bf(tile[p][cg * 4 + 2]);
      o.w = f2bf(tile[p][cg * 4 + 3]);
      *(ushort4*)(ob + (((size_t)(p0 + p)) << 8) + c0 + cg * 4) = o;
    }
  } else {
    int gid = (bx - 2048) * 256 + t;
    const int N1 = 72 * 8192;
    const int N2 = 32 * KDIM;
    if (gid < N1) {
      int j = gid & 7;
      int lane = (gid >> 3) & 63;
      int mb = (gid >> 9) & 15;
      int kc = gid >> 13;
      int row = mb * 16 + (lane & 15);
      int gk = kc * 32 + ((lane >> 4) << 3) + j;
      int c = gk & 255, kidx = gk >> 8;
      Wpk[gid] = f2bf(dcn_w[((size_t)(row * 256 + c)) * 9 + kidx]);
    } else if (gid < N1 + N2) {
      int g = gid - N1;
      int ch = g / KDIM, k = g % KDIM;
      int kidx = k >> 8, c = k & 255;
      Wob[g] = (ch < 27) ? f2bf(offset_w[((size_t)(ch * 256 + c)) * 9 + kidx])
                         : (unsigned short)0;
    } else if (gid < N1 + N2 + 128) {
      zp[gid - N1 - N2] = 0;
    }
  }
}

// ---------------------------------------------------------------------------
// Kernel 2: offset conv GEMM + sampling-table epilogue (R7 verbatim:
//  grid 512, 256 thr / 4 waves, BK=32, 4-buffer depth-3, ONE barrier/iter).
// ---------------------------------------------------------------------------
__global__ __launch_bounds__(256) void k_offs(const unsigned short* __restrict__ xTb,
                                              const unsigned short* __restrict__ Wob,
                                              const unsigned short* __restrict__ zp,
                                              const float* __restrict__ offb,
                                              float* __restrict__ SW) {
  __shared__ unsigned short As[4][32 * 32];
  __shared__ unsigned short Bsf[4][32 * 32];
  __shared__ float Os[32][33];
  int t = threadIdx.x;
  int wv = t >> 6, lane = t & 63;
  int bid = (int)blockIdx.x;
  int swz = (bid & 7) * 64 + (bid >> 3);
  int n0 = swz * 32;

  int r0 = (t >> 2) & 31, coff = (t & 3) * 8;
  int rowA = n0 + r0;
  int b_ = rowA >> 12, hw = rowA & 4095, h = hw >> 6, w = hw & 63;
  int rB = ((t - 128) >> 2) & 31;

  f32x4 acc = {};

  auto stage = [&](int kt) {
    int buf = kt & 3;
    int k0 = kt * 32;
    int kidx = k0 >> 8, c0 = k0 & 255;
    if (t < 128) {
      int di = kidx / 3 - 1, dj = kidx % 3 - 1;
      int y = h + di, xx = w + dj;
      const unsigned short* g = (y >= 0 && y < 64 && xx >= 0 && xx < 64)
          ? xTb + (((((size_t)b_) << 12) + (y << 6) + xx) << 8) + c0 + coff
          : zp;
      gl2lds16(g, (char*)As[buf] + wv * 1024);
    } else {
      const unsigned short* gB = Wob + (size_t)rB * KDIM + k0 + coff;
      gl2lds16(gB, (char*)Bsf[buf] + (wv - 2) * 1024);
    }
  };

  stage(0); stage(1); stage(2);

  int mf = wv & 1, nf = wv >> 1;
  for (int kt = 0; kt < 72; ++kt) {
    if (kt <= 69)      asm volatile("s_waitcnt vmcnt(2)" ::: "memory");
    else if (kt == 70) asm volatile("s_waitcnt vmcnt(1)" ::: "memory");
    else               asm volatile("s_waitcnt vmcnt(0)" ::: "memory");
    asm volatile("s_barrier" ::: "memory");
    if (kt + 3 < 72) stage(kt + 3);
    int buf = kt & 3;
    bf16x8 aF = *(const bf16x8*)(As[buf] + (mf * 16 + (lane & 15)) * 32 + (lane >> 4) * 8);
    bf16x8 bF = *(const bf16x8*)(Bsf[buf] + (nf * 16 + (lane & 15)) * 32 + (lane >> 4) * 8);
    acc = __builtin_amdgcn_mfma_f32_16x16x32_bf16(aF, bF, acc, 0, 0, 0);
  }

  int quad = lane >> 4, cl = lane & 15;
#pragma unroll
  for (int rr = 0; rr < 4; ++rr)
    Os[mf * 16 + quad * 4 + rr][nf * 16 + cl] = acc[rr];
  __syncthreads();

  for (int item = t; item < 288; item += 256) {
    int bl = item & 31, k = item >> 5;
    int bhw = n0 + bl;
    int h_ = (bhw >> 6) & 63, w_ = bhw & 63;
    float dy = Os[bl][2 * k]     + offb[2 * k];
    float dx = Os[bl][2 * k + 1] + offb[2 * k + 1];
    float mv = Os[bl][18 + k]    + offb[18 + k];
    float mask = 1.0f / (1.0f + expf(-mv));

    float py = (float)(h_ - 1 + k / 3) + dy;
    float px = (float)(w_ - 1 + k % 3) + dx;
    float y0f = floorf(py), x0f = floorf(px);
    float wy = py - y0f, wx = px - x0f;
    int y0 = (int)y0f, x0 = (int)x0f;
    int y1 = y0 + 1, x1 = x0 + 1;

    float vy0 = (y0 >= 0 && y0 < 64) ? 1.f : 0.f;
    float vy1 = (y1 >= 0 && y1 < 64) ? 1.f : 0.f;
    float vx0 = (x0 >= 0 && x0 < 64) ? 1.f : 0.f;
    float vx1 = (x1 >= 0 && x1 < 64) ? 1.f : 0.f;
    int y0c = min(max(y0, 0), 63), y1c = min(max(y1, 0), 63);
    int x0c = min(max(x0, 0), 63), x1c = min(max(x1, 0), 63);

    float4 wv4;
    wv4.x = (1.f - wy) * (1.f - wx) * vy0 * vx0 * mask;
    wv4.y = (1.f - wy) * wx * vy0 * vx1 * mask;
    wv4.z = wy * (1.f - wx) * vy1 * vx0 * mask;
    wv4.w = wy * wx * vy1 * vx1 * mask;
    uint4 ov;
    ov.x = (unsigned)(((y0c << 6) + x0c) << 8);
    ov.y = (unsigned)(((y0c << 6) + x1c) << 8);
    ov.z = (unsigned)(((y1c << 6) + x0c) << 8);
    ov.w = (unsigned)(((y1c << 6) + x1c) << 8);

    float* p = SW + (size_t)(k * 16384 + bhw) * 8;
    *(float4*)p = wv4;
    *(uint4*)(p + 4) = ov;
  }
}

// ---------------------------------------------------------------------------
// Kernel 3: fused sample + main GEMM -- R7 VERBATIM (best measured: 131.6us
//  total). BK=64 phases (36), asm-pinned loads, counted vmcnt, SW in LDS.
//  Session conclusion: this kernel's ~43us is invariant to barrier drain,
//  pipeline depth, phase count, occupancy (x2 both ways), L2 byte cuts, and
//  setprio -- consistent with a VMEM scatter-processing floor structural to
//  DCNv2's data-dependent bilinear gather (4 corners x 64B granules).
// ---------------------------------------------------------------------------
#define PHASE(PH, Q, AF, BUF, WB, WM)                                          \
  do {                                                                         \
    if (((PH) & 3) == 0) {                                                     \
      int g_ = (PH) >> 2;                                                      \
      wv4 = *(const float4*)(SWL + (size_t)(g_ * 128 + r * 2) * 4);            \
      ov  = *(const uint4*)(SWL + (size_t)(g_ * 128 + r * 2 + 1) * 4);         \
    } else if (((PH) & 3) == 2 && (PH) < 32) {                                 \
      ov  = *(const uint4*)(SWL + (size_t)((((PH) >> 2) + 1) * 128 + r * 2 + 1) * 4); \
    }                                                                          \
    asm volatile("s_waitcnt vmcnt(" #WB ")" ::: "memory");                     \
    __builtin_amdgcn_sched_barrier(0);                                         \
    float s_[8];                                                               \
    _Pragma("unroll")                                                          \
    for (int j_ = 0; j_ < 8; ++j_)                                             \
      s_[j_] = wv4.x * bf2f((unsigned short)Q[0][j_]) +                        \
               wv4.y * bf2f((unsigned short)Q[1][j_]) +                        \
               wv4.z * bf2f((unsigned short)Q[2][j_]) +                        \
               wv4.w * bf2f((unsigned short)Q[3][j_]);                         \
    union { __hip_bfloat162 h2[4]; bf16x8 v; } pk_;                            \
    pk_.h2[0] = __float22bfloat162_rn(make_float2(s_[0], s_[1]));              \
    pk_.h2[1] = __float22bfloat162_rn(make_float2(s_[2], s_[3]));              \
    pk_.h2[2] = __float22bfloat162_rn(make_float2(s_[4], s_[5]));              \
    pk_.h2[3] = __float22bfloat162_rn(make_float2(s_[6], s_[7]));              \
    *(bf16x8*)(&Bs[BUF][s_th][bsw]) = pk_.v;                                   \
    if ((PH) < 34) {                                                           \
      int kn0_ = 2 * (PH) + 4;                                                 \
      unsigned c_ = (unsigned)((((kn0_ & 7) + s_th) << 5) + gg * 8);           \
      GLOAD16(Q[0], xb + ov.x + c_);                                           \
      GLOAD16(Q[1], xb + ov.y + c_);                                           \
      GLOAD16(Q[2], xb + ov.z + c_);                                           \
      GLOAD16(Q[3], xb + ov.w + c_);                                           \
    }                                                                          \
    asm volatile("s_waitcnt vmcnt(" #WM ") lgkmcnt(0)\n\ts_barrier" ::: "memory"); \
    __builtin_amdgcn_sched_barrier(0);                                         \
    _Pragma("unroll")                                                          \
    for (int s2_ = 0; s2_ < 2; ++s2_) {                                        \
      bf16x8 bF0_ = *(const bf16x8*)(                                          \
          &Bs[BUF][s2_][(wn * 32 + (lane & 15)) * 56 + (lane >> 4) * 8]);      \
      bf16x8 bF1_ = *(const bf16x8*)(                                          \
          &Bs[BUF][s2_][(wn * 32 + 16 + (lane & 15)) * 56 + (lane >> 4) * 8]); \
      _Pragma("unroll")                                                        \
      for (int i_ = 0; i_ < 4; ++i_) {                                         \
        acc[i_][0] = __builtin_amdgcn_mfma_f32_16x16x32_bf16(                  \
            AF[s2_ * 4 + i_], bF0_, acc[i_][0], 0, 0, 0);                      \
        acc[i_][1] = __builtin_amdgcn_mfma_f32_16x16x32_bf16(                  \
            AF[s2_ * 4 + i_], bF1_, acc[i_][1], 0, 0, 0);                      \
      }                                                                        \
    }                                                                          \
    if ((PH) < 34) {                                                           \
      _Pragma("unroll")                                                        \
      for (int i_ = 0; i_ < 8; ++i_) {                                         \
        const unsigned short* ap_ =                                            \
            wpBase + ((size_t)((2 * (PH) + 4 + (i_ >> 2)) * 16 + (i_ & 3))) * 512; \
        GLOAD16(AF[i_], ap_);                                                  \
      }                                                                        \
    }                                                                          \
  } while (0)

__global__ __launch_bounds__(512, 2) void k_fused(const unsigned short* __restrict__ Wpk,
                                                  const unsigned short* __restrict__ xTb,
                                                  const float* __restrict__ SW,
                                                  float* __restrict__ out) {
  __shared__ __align__(16) unsigned short Bs[2][2][64 * 56];  // 28 KB
  __shared__ __align__(16) float SWL[1152 * 4];               // 18 KB
  int t = threadIdx.x;
  int wv = t >> 6, lane = t & 63;
  int wm = wv & 3, wn = wv >> 2;
  int bid = (int)blockIdx.x;
  int swz = (bid & 7) * 32 + (bid >> 3);   // XCD-contiguous chunks (256 = 8*32)
  int n0 = swz * 64;
  int b  = n0 >> 12;
  const unsigned short* xb = xTb + ((size_t)b << 20);

  // sampling role: row r (0..63); u = t&7 -> substep s_th, ch-group gg (8 ch)
  int r = t >> 3;
  int u = t & 7;
  int s_th = u & 1, gg = u >> 1;
  int bsw = r * 56 + gg * 8;

  const unsigned short* wpBase = Wpk + ((size_t)(wm * 4 * 64 + lane)) * 8;

  f32x4 acc[4][2] = {};

  // --- stage SW table (64 rows x 9 groups x 32B = 18KB) into LDS ---
  {
#pragma unroll
    for (int i = 0; i < 3; ++i) {
      int hs = t + i * 512;
      if (hs < 1152) {
        int grp = hs >> 7, row = (hs >> 1) & 63, hh = hs & 1;
        const float* src = SW + ((size_t)(grp * 16384 + n0 + row)) * 8 + hh * 4;
        char* dstbase = (char*)SWL + ((size_t)((t & ~63) + i * 512)) * 16;
        gl2lds16(src, dstbase);
      }
    }
  }
  asm volatile("s_waitcnt vmcnt(0)" ::: "memory");
  __builtin_amdgcn_s_barrier();

  float4 wv4; uint4 ov;
  wv4 = *(const float4*)(SWL + (size_t)(r * 2) * 4);
  ov  = *(const uint4*)(SWL + (size_t)(r * 2 + 1) * 4);

  bf16x8 qA[4], qB[4];
  bf16x8 aFA[8], aFB[8];

  // prologue loads in canonical order: q(0), aF(0), q(1), aF(1)
  {
    unsigned cA = (unsigned)((s_th << 5) + gg * 8);
    GLOAD16(qA[0], xb + ov.x + cA);
    GLOAD16(qA[1], xb + ov.y + cA);
    GLOAD16(qA[2], xb + ov.z + cA);
    GLOAD16(qA[3], xb + ov.w + cA);
#pragma unroll
    for (int i = 0; i < 8; ++i) {
      const unsigned short* ap = wpBase + ((size_t)(((i >> 2)) * 16 + (i & 3))) * 512;
      GLOAD16(aFA[i], ap);
    }
    unsigned cB = (unsigned)(((2 + s_th) << 5) + gg * 8);
    GLOAD16(qB[0], xb + ov.x + cB);
    GLOAD16(qB[1], xb + ov.y + cB);
    GLOAD16(qB[2], xb + ov.z + cB);
    GLOAD16(qB[3], xb + ov.w + cB);
#pragma unroll
    for (int i = 0; i < 8; ++i) {
      const unsigned short* ap = wpBase + ((size_t)((2 + (i >> 2)) * 16 + (i & 3))) * 512;
      GLOAD16(aFB[i], ap);
    }
  }

  for (int ph = 0; ph < 34; ph += 2) {       // phases 0..33
    PHASE(ph,     qA, aFA, 0, 20, 16);
    PHASE(ph + 1, qB, aFB, 1, 20, 16);
  }
  PHASE(34, qA, aFA, 0, 20, 12);
  PHASE(35, qB, aFB, 1, 8, 0);

  // epilogue
  int quad = lane >> 4, cl = lane & 15;
  float* ob = out + (((size_t)b) << 20);
#pragma unroll
  for (int i = 0; i < 4; ++i) {
    int mbase = wm * 64 + i * 16 + quad * 4;
#pragma unroll
    for (int j = 0; j < 2; ++j) {
      int hw = (n0 & 4095) + wn * 32 + j * 16 + cl;
      float* op = ob + hw;
#pragma unroll
      for (int rr = 0; rr < 4; ++rr)
        op[((size_t)(mbase + rr)) << 12] = acc[i][j][rr];
    }
  }
}

// ---------------------------------------------------------------------------
extern "C" void kernel_launch(void* const* d_in, const int* in_sizes, int n_in,
                              void* d_out, int out_size, void* d_ws, size_t ws_size,
                              hipStream_t stream) {
  const float* x        = (const float*)d_in[0];
  const float* offset_w = (const float*)d_in[1];
  const float* offset_b = (const float*)d_in[2];
  const float* dcn_w    = (const float*)d_in[3];
  float* out = (float*)d_out;

  char* ws = (char*)d_ws;
  size_t off = 0;
  auto carve = [&](size_t bytes) -> void* {
    void* p = ws + off;
    off += (bytes + 255) & ~(size_t)255;
    return p;
  };
  unsigned short* xTb = (unsigned short*)carve(4ull * 64 * 64 * 256 * 2);   // 8 MB
  unsigned short* Wpk = (unsigned short*)carve(72ull * 8192 * 2);           // 1.125 MB
  unsigned short* Wob = (unsigned short*)carve(32ull * KDIM * 2);           // 144 KB
  unsigned short* zp  = (unsigned short*)carve(256);                        // zero page
  float*          SW  = (float*)carve(9ull * 16384 * 8 * 4);                // 4.5 MB
  (void)ws_size; (void)in_sizes; (void)n_in; (void)out_size;

  const int WPREP_BLOCKS = (72 * 8192 + 32 * KDIM + 128 + 255) / 256;
  k_prep<<<dim3(2048 + WPREP_BLOCKS), 256, 0, stream>>>(
      x, xTb, dcn_w, offset_w, Wpk, Wob, zp);
  k_offs<<<dim3(512), 256, 0, stream>>>(xTb, Wob, zp, offset_b, SW);
  k_fused<<<dim3(256), 512, 0, stream>>>(Wpk, xTb, SW, out);
}